// Round 2
// baseline (169.679 us; speedup 1.0000x reference)
//
#include <hip/hip_runtime.h>

#define N_ATOMS 50000
#define N_PAIRS 1600000
#define FDIM 128

typedef short short8 __attribute__((ext_vector_type(8)));
typedef float floatx4 __attribute__((ext_vector_type(4)));

// fp32 -> bf16 round-to-nearest-even
__device__ inline ushort f2bf(float f) {
    union { float f; unsigned u; } v; v.f = f;
    unsigned lsb = (v.u >> 16) & 1u;
    return (ushort)((v.u + 0x7fffu + lsb) >> 16);
}
__device__ inline float bflo(unsigned u) { return __uint_as_float(u << 16); }
__device__ inline float bfhi(unsigned u) { return __uint_as_float(u & 0xffff0000u); }

#define GEMM_BLOCKS 782   // ceil(50000/64) rows
#define RP_BLOCKS   196   // ceil(50001/256)

// ---------------------------------------------------------------------------
// K1: fused (independent jobs by blockIdx):
//   [0, 782):    v = bf16(x @ W^T) via mfma_f32_16x16x32_bf16
//   [782, 978):  rowptr[i] = lower_bound(idx_i, i)
// ---------------------------------------------------------------------------
__global__ __launch_bounds__(256) void gemm_rowptr(const float* __restrict__ x,
                                                   const float* __restrict__ W,
                                                   const int* __restrict__ idx_i,
                                                   ushort* __restrict__ v,
                                                   int* __restrict__ rowptr) {
    const int t = threadIdx.x;
    if (blockIdx.x >= GEMM_BLOCKS) {
        const int i = (blockIdx.x - GEMM_BLOCKS) * 256 + t;
        if (i > N_ATOMS) return;
        int lo = 0, hi = N_PAIRS;
        while (lo < hi) {
            int mid = (lo + hi) >> 1;
            if (idx_i[mid] < i) lo = mid + 1; else hi = mid;
        }
        rowptr[i] = lo;
        return;
    }

    __shared__ ushort Wsh[128 * 136];
#pragma unroll
    for (int u = 0; u < 16; ++u) {
        int id = t + 256 * u;
        int f  = id >> 5;
        int k4 = (id & 31) * 4;
        const float4 w4 = *(const float4*)(W + f * FDIM + k4);
        ushort* d = &Wsh[f * 136 + k4];
        d[0] = f2bf(w4.x); d[1] = f2bf(w4.y); d[2] = f2bf(w4.z); d[3] = f2bf(w4.w);
    }
    __syncthreads();

    const int lane = t & 63, wv = t >> 6;
    const int mrow = lane & 15, q = lane >> 4;
    const int mw   = blockIdx.x * 64 + wv * 16;

    int row = mw + mrow;
    if (row >= N_ATOMS) row = N_ATOMS - 1;   // clamped reads; stores guarded
    const float* xr = x + (long)row * FDIM + 8 * q;

    short8 a[4];
#pragma unroll
    for (int kc = 0; kc < 4; ++kc) {
        const float4 lo4 = *(const float4*)(xr + 32 * kc);
        const float4 hi4 = *(const float4*)(xr + 32 * kc + 4);
        short8 af;
        af[0] = f2bf(lo4.x); af[1] = f2bf(lo4.y); af[2] = f2bf(lo4.z); af[3] = f2bf(lo4.w);
        af[4] = f2bf(hi4.x); af[5] = f2bf(hi4.y); af[6] = f2bf(hi4.z); af[7] = f2bf(hi4.w);
        a[kc] = af;
    }

    floatx4 acc[8];
#pragma unroll
    for (int f = 0; f < 8; ++f) acc[f] = (floatx4)(0.f);

#pragma unroll
    for (int f = 0; f < 8; ++f) {
        const ushort* wr = &Wsh[(16 * f + mrow) * 136 + 8 * q];
#pragma unroll
        for (int kc = 0; kc < 4; ++kc)
            acc[f] = __builtin_amdgcn_mfma_f32_16x16x32_bf16(a[kc], *(const short8*)(wr + 32 * kc), acc[f], 0, 0, 0);
    }

#pragma unroll
    for (int f = 0; f < 8; ++f) {
#pragma unroll
        for (int r = 0; r < 4; ++r) {
            const int orow = mw + 4 * q + r;
            if (orow < N_ATOMS)
                v[(long)orow * FDIM + 16 * f + mrow] = f2bf(acc[f][r]);
        }
    }
}

// ---------------------------------------------------------------------------
// K2 (r1 restructure): XCD-feature-sliced gather.
// Old form: every XCD gathers full 256 B v-rows from all 12.8 MB of v ->
// v must replicate into all 8 L2s (FETCH pinned ~156 MB, 49.4 us, latency-
// bound at 3.2 TB/s with VALUBusy 38% / HBM 47% / Mfma 0 -- nothing
// saturated).
// New form: feature dim split into 4 slices of 32 feats (64 B). Slice s is
// handled only by blocks with blockIdx%8 in {2s,2s+1} (round-robin XCD
// mapping, perf-only assumption): per-XCD v working set = 3.2 MB -> L2-
// RESIDENT; gathers become L2 hits. idx/alpha become 4x-duplicated
// streaming reads (51 MB). Total FMA/gather/idx instruction work conserved
// (each pair's 128 feats processed once across the 4 slice-jobs).
// One wave = one (atom, slice): lane = g(pair 0..15) x c(16B chunk 0..3);
// 16 pairs per gather instr; shfl-xor(4,8,16,32) reduce; 128 B store.
// ---------------------------------------------------------------------------
__global__ __launch_bounds__(256) void scatter_y(const ushort* __restrict__ v,
                                                 const float* __restrict__ alpha,
                                                 const int* __restrict__ idx_j,
                                                 const int* __restrict__ rowptr,
                                                 float* __restrict__ y) {
    const int lane = threadIdx.x & 63;
    const int wv   = threadIdx.x >> 6;
    const int b    = blockIdx.x;          // 50000 blocks exactly (50000%8==0)
    const int T    = b & 7;               // XCD under round-robin dispatch
    const int G    = b >> 3;              // 0..6249
    const int slice = T >> 1;             // 0..3 : feats [32*slice, 32*slice+32)
    const int sub   = T & 1;
    const int atom  = ((G * 2 + sub) << 2) + wv;   // exact cover of [0,50000)

    const int g = lane >> 2;              // pair subgroup 0..15
    const int c = lane & 3;               // 16B chunk 0..3 within slice
    const char* vbase = (const char*)v + slice * 64 + (c << 4);

    const int start = __builtin_amdgcn_readfirstlane(rowptr[atom]);
    const int end   = __builtin_amdgcn_readfirstlane(rowptr[atom + 1]);

    float acc[8];
#pragma unroll
    for (int k = 0; k < 8; ++k) acc[k] = 0.f;

#pragma unroll 2
    for (int p0 = start; p0 < end; p0 += 16) {
        const int  pp    = p0 + g;
        const bool valid = pp < end;
        const int  pc    = valid ? pp : start;      // start < end inside loop
        const int  j     = idx_j[pc];
        float      a     = alpha[pc];
        a = valid ? a : 0.f;
        const uint4 vv = *(const uint4*)(vbase + ((unsigned)j << 8));
        acc[0] += a * bflo(vv.x); acc[1] += a * bfhi(vv.x);
        acc[2] += a * bflo(vv.y); acc[3] += a * bfhi(vv.y);
        acc[4] += a * bflo(vv.z); acc[5] += a * bfhi(vv.z);
        acc[6] += a * bflo(vv.w); acc[7] += a * bfhi(vv.w);
    }

    // reduce the 16 pair-subgroups (lane bits 2..5)
#pragma unroll
    for (int k = 0; k < 8; ++k) {
        acc[k] += __shfl_xor(acc[k], 4);
        acc[k] += __shfl_xor(acc[k], 8);
        acc[k] += __shfl_xor(acc[k], 16);
        acc[k] += __shfl_xor(acc[k], 32);
    }

    // lanes 0..15 store: lane = g2*4 + c, feats slice*32 + c*8 + 2*g2 + {0,1}
    if (lane < 16) {
        const float e0 = (g & 1) ? acc[2] : acc[0];
        const float e1 = (g & 1) ? acc[3] : acc[1];
        const float f0 = (g & 1) ? acc[6] : acc[4];
        const float f1 = (g & 1) ? acc[7] : acc[5];
        float2 o;
        o.x = (g & 2) ? f0 : e0;
        o.y = (g & 2) ? f1 : e1;
        *(float2*)(y + (long)atom * FDIM + slice * 32 + c * 8 + g * 2) = o;
    }
}

extern "C" void kernel_launch(void* const* d_in, const int* in_sizes, int n_in,
                              void* d_out, int out_size, void* d_ws, size_t ws_size,
                              hipStream_t stream) {
    const float* x     = (const float*)d_in[0];
    const float* alpha = (const float*)d_in[1];
    const int*   idx_i = (const int*)d_in[2];   // int32 per harness contract
    const int*   idx_j = (const int*)d_in[3];
    const float* W     = (const float*)d_in[4];
    float* y = (float*)d_out;

    // ws layout: v 12.8 MB | rowptr 200 KB
    ushort* v      = (ushort*)d_ws;
    int*    rowptr = (int*)((char*)d_ws + (size_t)N_ATOMS * FDIM * 2);

    gemm_rowptr<<<GEMM_BLOCKS + RP_BLOCKS, 256, 0, stream>>>(x, W, idx_i, v, rowptr);
    scatter_y<<<N_ATOMS, 256, 0, stream>>>(v, alpha, idx_j, rowptr, y);
}

// Round 3
// 140.561 us; speedup vs baseline: 1.2072x; 1.2072x over previous
//
#include <hip/hip_runtime.h>

#define N_ATOMS 50000
#define N_PAIRS 1600000
#define FDIM 128

typedef short short8 __attribute__((ext_vector_type(8)));
typedef float floatx4 __attribute__((ext_vector_type(4)));

// fp32 -> bf16 round-to-nearest-even
__device__ inline ushort f2bf(float f) {
    union { float f; unsigned u; } v; v.f = f;
    unsigned lsb = (v.u >> 16) & 1u;
    return (ushort)((v.u + 0x7fffu + lsb) >> 16);
}
__device__ inline float bflo(unsigned u) { return __uint_as_float(u << 16); }
__device__ inline float bfhi(unsigned u) { return __uint_as_float(u & 0xffff0000u); }

#define GEMM_BLOCKS 782   // ceil(50000/64) rows
#define RP_BLOCKS   196   // ceil(50001/256)

// ---------------------------------------------------------------------------
// K1: fused (independent jobs by blockIdx):
//   [0, 782):    v = bf16(x @ W^T) via mfma_f32_16x16x32_bf16
//   [782, 978):  rowptr[i] = lower_bound(idx_i, i)
// ---------------------------------------------------------------------------
__global__ __launch_bounds__(256) void gemm_rowptr(const float* __restrict__ x,
                                                   const float* __restrict__ W,
                                                   const int* __restrict__ idx_i,
                                                   ushort* __restrict__ v,
                                                   int* __restrict__ rowptr) {
    const int t = threadIdx.x;
    if (blockIdx.x >= GEMM_BLOCKS) {
        const int i = (blockIdx.x - GEMM_BLOCKS) * 256 + t;
        if (i > N_ATOMS) return;
        int lo = 0, hi = N_PAIRS;
        while (lo < hi) {
            int mid = (lo + hi) >> 1;
            if (idx_i[mid] < i) lo = mid + 1; else hi = mid;
        }
        rowptr[i] = lo;
        return;
    }

    __shared__ ushort Wsh[128 * 136];
#pragma unroll
    for (int u = 0; u < 16; ++u) {
        int id = t + 256 * u;
        int f  = id >> 5;
        int k4 = (id & 31) * 4;
        const float4 w4 = *(const float4*)(W + f * FDIM + k4);
        ushort* d = &Wsh[f * 136 + k4];
        d[0] = f2bf(w4.x); d[1] = f2bf(w4.y); d[2] = f2bf(w4.z); d[3] = f2bf(w4.w);
    }
    __syncthreads();

    const int lane = t & 63, wv = t >> 6;
    const int mrow = lane & 15, q = lane >> 4;
    const int mw   = blockIdx.x * 64 + wv * 16;

    int row = mw + mrow;
    if (row >= N_ATOMS) row = N_ATOMS - 1;   // clamped reads; stores guarded
    const float* xr = x + (long)row * FDIM + 8 * q;

    short8 a[4];
#pragma unroll
    for (int kc = 0; kc < 4; ++kc) {
        const float4 lo4 = *(const float4*)(xr + 32 * kc);
        const float4 hi4 = *(const float4*)(xr + 32 * kc + 4);
        short8 af;
        af[0] = f2bf(lo4.x); af[1] = f2bf(lo4.y); af[2] = f2bf(lo4.z); af[3] = f2bf(lo4.w);
        af[4] = f2bf(hi4.x); af[5] = f2bf(hi4.y); af[6] = f2bf(hi4.z); af[7] = f2bf(hi4.w);
        a[kc] = af;
    }

    floatx4 acc[8];
#pragma unroll
    for (int f = 0; f < 8; ++f) acc[f] = (floatx4)(0.f);

#pragma unroll
    for (int f = 0; f < 8; ++f) {
        const ushort* wr = &Wsh[(16 * f + mrow) * 136 + 8 * q];
#pragma unroll
        for (int kc = 0; kc < 4; ++kc)
            acc[f] = __builtin_amdgcn_mfma_f32_16x16x32_bf16(a[kc], *(const short8*)(wr + 32 * kc), acc[f], 0, 0, 0);
    }

#pragma unroll
    for (int f = 0; f < 8; ++f) {
#pragma unroll
        for (int r = 0; r < 4; ++r) {
            const int orow = mw + 4 * q + r;
            if (orow < N_ATOMS)
                v[(long)orow * FDIM + 16 * f + mrow] = f2bf(acc[f][r]);
        }
    }
}

// ---------------------------------------------------------------------------
// K2 (r3): XCD-sliced gather, v2 — 2 slices x 128 B (one full cache line).
// r2 post-mortem: 64 B slices wasted half of every fetched 128 B line and
// duplicated idx/alpha 4x -> FETCH 156->213 MB, 49->85 us. This version
// fixes all three causes: slice = 64 feats = 128 B (zero line waste),
// idx/alpha dup only 2x, wave-jobs only 2x (100k, avg 4 iters each).
// Per-XCD v working set = 50000 x 128 B = 6.4 MB (halved); v compulsory
// L3->L2 duplication 102 -> ~51 MB. blockIdx%8 -> XCD round-robin is a
// perf-only assumption.
// Wave = one (atom, slice): lane = g(pair 0..7) x c(16B chunk 0..7);
// dwordx4 gathers 8 rows/instr; shfl-xor(8,16,32) reduce; lanes 0..7
// store 2x float4 (256 B/wave, coalesced).
// Falsification: FETCH >= 130 MB or dur >= 49 us -> revert to r1 shape.
// ---------------------------------------------------------------------------
__global__ __launch_bounds__(256) void scatter_y(const ushort* __restrict__ v,
                                                 const float* __restrict__ alpha,
                                                 const int* __restrict__ idx_j,
                                                 const int* __restrict__ rowptr,
                                                 float* __restrict__ y) {
    const int lane = threadIdx.x & 63;
    const int wv   = threadIdx.x >> 6;
    const int b    = blockIdx.x;          // 25000 blocks
    const int T    = b & 7;               // XCD under round-robin dispatch
    const int G    = b >> 3;              // 0..3124
    const int slice = T & 1;              // 0/1 : feats [64*slice, 64*slice+64)
    const int sub   = T >> 1;             // 0..3
    const int atom  = ((G * 4 + sub) << 2) + wv;   // exact cover of [0,50000)

    const int g = lane >> 3;              // pair subgroup 0..7
    const int c = lane & 7;               // 16B chunk 0..7 within 128B slice
    const char* vbase = (const char*)v + slice * 128 + (c << 4);

    const int start = __builtin_amdgcn_readfirstlane(rowptr[atom]);
    const int end   = __builtin_amdgcn_readfirstlane(rowptr[atom + 1]);

    float acc[8];
#pragma unroll
    for (int k = 0; k < 8; ++k) acc[k] = 0.f;

#pragma unroll 4
    for (int p0 = start; p0 < end; p0 += 8) {
        const int  pp    = p0 + g;
        const bool valid = pp < end;
        const int  pc    = valid ? pp : start;      // start < end inside loop
        const int  j     = idx_j[pc];
        float      a     = alpha[pc];
        a = valid ? a : 0.f;
        const uint4 vv = *(const uint4*)(vbase + ((unsigned)j << 8));
        acc[0] += a * bflo(vv.x); acc[1] += a * bfhi(vv.x);
        acc[2] += a * bflo(vv.y); acc[3] += a * bfhi(vv.y);
        acc[4] += a * bflo(vv.z); acc[5] += a * bfhi(vv.z);
        acc[6] += a * bflo(vv.w); acc[7] += a * bfhi(vv.w);
    }

    // reduce the 8 pair-subgroups (lane bits 3..5)
#pragma unroll
    for (int k = 0; k < 8; ++k) {
        acc[k] += __shfl_xor(acc[k], 8);
        acc[k] += __shfl_xor(acc[k], 16);
        acc[k] += __shfl_xor(acc[k], 32);
    }

    // lanes 0..7 (g==0): lane c holds feats slice*64 + c*8 + [0,8)
    if (lane < 8) {
        float4 o0, o1;
        o0.x = acc[0]; o0.y = acc[1]; o0.z = acc[2]; o0.w = acc[3];
        o1.x = acc[4]; o1.y = acc[5]; o1.z = acc[6]; o1.w = acc[7];
        float* dst = y + (long)atom * FDIM + slice * 64 + c * 8;
        *(float4*)(dst)     = o0;
        *(float4*)(dst + 4) = o1;
    }
}

extern "C" void kernel_launch(void* const* d_in, const int* in_sizes, int n_in,
                              void* d_out, int out_size, void* d_ws, size_t ws_size,
                              hipStream_t stream) {
    const float* x     = (const float*)d_in[0];
    const float* alpha = (const float*)d_in[1];
    const int*   idx_i = (const int*)d_in[2];   // int32 per harness contract
    const int*   idx_j = (const int*)d_in[3];
    const float* W     = (const float*)d_in[4];
    float* y = (float*)d_out;

    // ws layout: v 12.8 MB | rowptr 200 KB
    ushort* v      = (ushort*)d_ws;
    int*    rowptr = (int*)((char*)d_ws + (size_t)N_ATOMS * FDIM * 2);

    gemm_rowptr<<<GEMM_BLOCKS + RP_BLOCKS, 256, 0, stream>>>(x, W, idx_i, v, rowptr);
    scatter_y<<<25000, 256, 0, stream>>>(v, alpha, idx_j, rowptr, y);
}